// Round 22
// baseline (21282.924 us; speedup 1.0000x reference)
//
#include <hip/hip_runtime.h>
#include <hip/hip_bf16.h>

#define T_STEPS 512
#define BATCH   64
#define HID     1024
#define NLAYER  3
#define EPSV    1e-5f
#define LDS_BYTES 147584
#define NBLK    256

typedef __attribute__((ext_vector_type(8))) short    short8;
typedef __attribute__((ext_vector_type(8))) _Float16 f16x8;
typedef __attribute__((ext_vector_type(4))) float    f32x4;

// packed activation layout within one [64 rows x 1024 k] fp16 buffer (65536 elems):
// [kc(8)][mt(4)][ki(4)][lane(64)][j(8)]  where row = mt*16 + (lane&15),
// k = kc*128 + ki*32 + (lane>>4)*8 + j
__device__ __forceinline__ int act_pack_idx(int row, int k) {
  int mt = row >> 4, lr = row & 15;
  int kc = k >> 7;
  int ki = (k >> 5) & 3;
  int lh = (k >> 3) & 3;
  int j  = k & 7;
  int lane = lr | (lh << 4);
  return ((((kc * 4 + mt) * 4 + ki) * 64) + lane) * 8 + j;
}

__device__ __forceinline__ float sigmoidf_(float v) {
  return 1.f / (1.f + __expf(-v));
}

// ---- write-through (coherent) stores ----
__device__ __forceinline__ void st_dword_sc(void* p, unsigned v) {
  asm volatile("global_store_dword %0, %1, off sc0 sc1"
               :: "v"(p), "v"(v) : "memory");
}
__device__ __forceinline__ void st_dwordx2_sc(void* p, unsigned long long v) {
  asm volatile("global_store_dwordx2 %0, %1, off sc0 sc1"
               :: "v"(p), "v"(v) : "memory");
}
// ---- coherent 8B load (bypasses L1/L2, reads coherence point) ----
__device__ __forceinline__ unsigned long long ld_u64_sc(const void* p) {
  return __hip_atomic_load((const unsigned long long*)p,
                           __ATOMIC_RELAXED, __HIP_MEMORY_SCOPE_SYSTEM);
}

// release (all this block's sc-stores at L3) then fire-and-forget arrival
__device__ __forceinline__ void arrive(int* cnt) {
  asm volatile("s_waitcnt vmcnt(0)" ::: "memory");
  __syncthreads();
  if (threadIdx.x == 0)
    (void)__hip_atomic_fetch_add(cnt, 1, __ATOMIC_RELAXED,
                                 __HIP_MEMORY_SCOPE_AGENT);
}
// wait for a monotonic counter to reach target (tid0 polls, block syncs)
__device__ __forceinline__ void waitcnt_ge(int* cnt, int target) {
  if (threadIdx.x == 0) {
    while (__hip_atomic_load(cnt, __ATOMIC_RELAXED,
                             __HIP_MEMORY_SCOPE_AGENT) < target)
      __builtin_amdgcn_s_sleep(1);
  }
  __syncthreads();
}

// Full gbar (used ONCE for rank registration): parallel flags + block-0 agg.
__device__ __forceinline__ void gbar(int* farr, int* epoch, int k) {
  asm volatile("s_waitcnt vmcnt(0)" ::: "memory");
  __syncthreads();
  const int tid = threadIdx.x;
  if (blockIdx.x == 0) {
    if (tid > 0 && tid < NBLK) {
      while (__hip_atomic_load(&farr[tid * 16], __ATOMIC_RELAXED,
                               __HIP_MEMORY_SCOPE_AGENT) < k)
        __builtin_amdgcn_s_sleep(1);
    }
    __syncthreads();
    if (tid == 0)
      __hip_atomic_store(epoch, k, __ATOMIC_RELAXED, __HIP_MEMORY_SCOPE_AGENT);
  } else {
    if (tid == 0) {
      __hip_atomic_store(&farr[blockIdx.x * 16], k, __ATOMIC_RELAXED,
                         __HIP_MEMORY_SCOPE_AGENT);
      while (__hip_atomic_load(epoch, __ATOMIC_RELAXED,
                               __HIP_MEMORY_SCOPE_AGENT) < k)
        __builtin_amdgcn_s_sleep(1);
    }
  }
  __syncthreads();
}

// Per-XCD barrier (R14 form): only the `count` blocks of one XCD participate.
__device__ __forceinline__ void xbar(int* xb, int xcd, int count, int k) {
  asm volatile("s_waitcnt vmcnt(0)" ::: "memory");
  __syncthreads();
  if (threadIdx.x == 0) {
    int* c = xb + xcd * 64;
    int* e = c + 16;
    int old = __hip_atomic_fetch_add(c, 1, __ATOMIC_RELAXED,
                                     __HIP_MEMORY_SCOPE_AGENT);
    if (old == count * k - 1)
      __hip_atomic_store(e, k, __ATOMIC_RELAXED, __HIP_MEMORY_SCOPE_AGENT);
    else
      while (__hip_atomic_load(e, __ATOMIC_RELAXED,
                               __HIP_MEMORY_SCOPE_AGENT) < k)
        __builtin_amdgcn_s_sleep(1);
  }
  __syncthreads();
}

// Wpack per layer: [ncb(64)][kc(16)][nt(4)][ki(4)][lane(64)][j(8)]
__global__ __launch_bounds__(256) void pack_weights(
    const float* __restrict__ Wx, const float* __restrict__ Wh,
    _Float16* __restrict__ Wpack) {
  long idx = (long)blockIdx.x * 256 + threadIdx.x;  // exactly 3*4096*2048 threads
  int l  = (int)(idx / 8388608);
  int r  = (int)(idx % 8388608);
  int ncb = r >> 17;
  int r2 = r & 131071;
  int kc = r2 >> 13;
  int r3 = r2 & 8191;
  int nt = r3 >> 11;
  int r4 = r3 & 2047;
  int ki = r4 >> 9;
  int r5 = r4 & 511;
  int lane = r5 >> 3, j = r5 & 7;
  int n = ncb * 64 + nt * 16 + (lane & 15);
  int k = kc * 128 + ki * 32 + ((lane >> 4) << 3) + j;
  float v = (k < 1024) ? Wx[((size_t)l * 4096 + n) * 1024 + k]
                       : Wh[((size_t)l * 4096 + n) * 1024 + (k - 1024)];
  Wpack[idx] = (_Float16)v;
}

// Pack x for ALL timesteps once. 131072 blocks x 256 threads.
__global__ __launch_bounds__(256) void pack_x(
    const float* __restrict__ x, _Float16* __restrict__ xpack) {
  int i = blockIdx.x * 256 + threadIdx.x;
  int t = i >> 16;
  int r = i & 65535;
  int b = r >> 10, e = r & 1023;
  xpack[(size_t)t * 65536 + act_pack_idx(b, e)] =
      (_Float16)x[((size_t)t * BATCH + b) * 1024 + e];
}

// zero ALL sync state (9216 ints) + zero the 3 h buffers.
// Threads = 9216 + 196608 = 205824 = 804*256 exactly.
__global__ __launch_bounds__(256) void init_all(
    _Float16* __restrict__ acts, int* __restrict__ flags) {
  int i = blockIdx.x * 256 + threadIdx.x;
  if (i < 9216) {
    flags[i] = 0;
  } else {
    ((unsigned short*)acts)[i - 9216] = 0;
  }
}

// sum-reduce two values across 512 threads (8 waves)
__device__ __forceinline__ void reduce2_512(float& a, float& b, float* red) {
  #pragma unroll
  for (int o = 32; o; o >>= 1) {
    a += __shfl_xor(a, o, 64);
    b += __shfl_xor(b, o, 64);
  }
  int wv = threadIdx.x >> 6;
  if ((threadIdx.x & 63) == 0) { red[wv * 2] = a; red[wv * 2 + 1] = b; }
  __syncthreads();
  a = red[0]; b = red[1];
  #pragma unroll
  for (int i = 1; i < 8; ++i) { a += red[i * 2]; b += red[i * 2 + 1]; }
  __syncthreads();
}

// Persistent kernel = R19 data paths exactly; sync restructured to
// split arrive/wait so barrier latency hides under compute:
//  - per-layer acnt[l]: every block arrives after its layer-l ifgo stores
//    (acnt[0] fills while blocks compute layers 1/2)
//  - B-duty block waits acnt[its l] (usually already satisfied), does B,
//    arrives at bcnt; everyone waits bcnt >= 192*(s+1)
//  - safety: bcnt full <= all B(2) arrived <= acnt[2] full <= every block
//    finished ALL xcdbuf reads -> next copy is WAR-safe; arrivals are
//    unconditional (ramp/drain still count) -> deadlock-free.
__global__ __launch_bounds__(512) __attribute__((amdgpu_waves_per_eu(2, 2)))
void lstm_main(
    const float* __restrict__ bh,
    const float* __restrict__ ln_g, const float* __restrict__ ln_b,
    const float* __restrict__ lnc_g, const float* __restrict__ lnc_b,
    const _Float16* __restrict__ Wpack, const _Float16* __restrict__ xpack,
    _Float16* __restrict__ acts, _Float16* __restrict__ xcdbuf,
    float* __restrict__ ifgo, float* __restrict__ out_all,
    int* __restrict__ flags) {
  extern __shared__ char smem[];
  _Float16* Wlds = (_Float16*)smem;              // [2][64 ks][64 lane][8] = 131072 B
  float*    lred = (float*)(smem + 131072);      // 16384 B
  float*    red  = (float*)(smem + 147456);      // 64 B
  int*      meta = (int*)(smem + 147520);        // rank/count
  int* acnt  = flags;                            // acnt[l] at flags[l*16], l=0..2
  int* bcnt  = flags + 48;
  int* epoch = flags + 64;                       // init gbar epoch
  int* xcnt  = flags + 128;                      // 8 x 16 ints
  int* xbarf = flags + 256;                      // 8 x 64 ints
  int* farr  = flags + 4096;                     // 256 x 16 ints (init gbar)
  const int bid = blockIdx.x, tid = threadIdx.x;
  const int wv = tid >> 6, lane = tid & 63;
  const int ncb = bid >> 2, ntp = bid & 3;

  int xcd_;
  asm("s_getreg_b32 %0, hwreg(HW_REG_XCC_ID)" : "=s"(xcd_));
  xcd_ &= 7;
  if (tid == 0)
    meta[0] = __hip_atomic_fetch_add(&xcnt[xcd_ * 16], 1, __ATOMIC_RELAXED,
                                     __HIP_MEMORY_SCOPE_AGENT);

  float c0r = 0.f, c1r = 0.f;   // c-state in registers (fixed B mapping)

  // ---- preload layers 0,1 weight frags into LDS (once) ----
  #pragma unroll
  for (int l = 0; l < 2; ++l)
    #pragma unroll
    for (int i = 0; i < 8; ++i) {
      const int idx = i * 512 + tid;        // 0..4095
      const int ks = idx >> 6, lj = idx & 63;
      const _Float16* src = Wpack
          + ((((size_t)(l * 64 + ncb) * 16 + (ks >> 2)) * 4 + ntp) * 4 + (ks & 3)) * 512
          + lj * 8;
      *(short8*)(Wlds + (l * 64 + ks) * 512 + lj * 8) = *(const short8*)src;
    }
  __syncthreads();

  gbar(farr, epoch, 1);                    // all blocks registered
  if (tid == 0)
    meta[1] = __hip_atomic_load(&xcnt[xcd_ * 16], __ATOMIC_RELAXED,
                                __HIP_MEMORY_SCOPE_AGENT);
  __syncthreads();
  const int rank = meta[0], cntx = meta[1];
  _Float16* xbase = xcdbuf + (size_t)xcd_ * 262144;   // 512 KB stride, 384 KB used

  for (int s = 0; s < T_STEPS + NLAYER - 1; ++s) {
    // ---- copy phase: 3 h-buffers (L3 truth) -> XCD-private (dirty L2) ----
    for (int c = rank * 512 + tid; c < 24576; c += cntx * 512) {
      f16x8 v;
      const _Float16* src = acts + c * 8;
      asm volatile("global_load_dwordx4 %0, %1, off sc0 sc1"
                   : "=v"(v) : "v"(src));
      asm volatile("s_waitcnt vmcnt(0)" ::: "memory");
      __builtin_amdgcn_sched_barrier(0);
      *(f16x8*)(xbase + c * 8) = v;        // plain store: dirty local L2
    }
    xbar(xbarf, xcd_, cntx, s + 1);

    // ---- W2 streamed weight frags (compiler-scheduled, L3) ----
    f16x8 Wst[8];
    if (s >= 2) {
      #pragma unroll
      for (int i = 0; i < 8; ++i) {
        const int ks = wv * 8 + i;
        Wst[i] = *(const f16x8*)(Wpack
            + ((((size_t)(2 * 64 + ncb) * 16 + (ks >> 2)) * 4 + ntp) * 4 + (ks & 3)) * 512
            + lane * 8);
      }
    }

    // ---------------- phase A: full-K GEMM per layer + arrive ----------------
    #pragma unroll
    for (int l = 0; l < 3; ++l) {
      const int t = s - l;
      if (t >= 0 && t < T_STEPS) {
        const bool a_is_x = (l == 0);
        const _Float16* aL = a_is_x ? (xpack + (size_t)t * 65536)
                                    : (xbase + (l - 1) * 65536);
        const _Float16* bL = xbase + l * 65536;
        f16x8 Wr[8];
        if (l < 2) {
          #pragma unroll
          for (int i = 0; i < 8; ++i)
            Wr[i] = *(const f16x8*)(Wlds + (l * 64 + wv * 8 + i) * 512 + lane * 8);
        } else {
          #pragma unroll
          for (int i = 0; i < 8; ++i) Wr[i] = Wst[i];
        }
        f32x4 acc[4];
        #pragma unroll
        for (int mt = 0; mt < 4; ++mt) acc[mt] = (f32x4){0.f, 0.f, 0.f, 0.f};
        #pragma unroll
        for (int mt = 0; mt < 4; ++mt) {
          f16x8 af[8];
          #pragma unroll
          for (int i = 0; i < 8; ++i) {
            const int ks = wv * 8 + i;           // 0..63
            const _Float16* hb = (ks < 32) ? aL : bL;
            const int ks2 = ks & 31;
            const _Float16* p = hb + (((ks2 >> 2) * 4 + mt) * 4 + (ks2 & 3)) * 512 + lane * 8;
            if (a_is_x && ks < 32) {
              af[i] = *(const f16x8*)p;          // static xpack: plain cached
            } else {
              asm volatile("global_load_dwordx4 %0, %1, off sc0"  // L1-bypass, L2-hit
                           : "=v"(af[i]) : "v"(p));
            }
          }
          asm volatile("s_waitcnt vmcnt(0)" ::: "memory");
          __builtin_amdgcn_sched_barrier(0);
          #pragma unroll
          for (int i = 0; i < 8; ++i)
            acc[mt] = __builtin_amdgcn_mfma_f32_16x16x32_f16(af[i], Wr[i], acc[mt], 0, 0, 0);
        }
        // two-pass cross-wave reduce in 16 KB lred
        __syncthreads();
        if (wv < 4) {
          #pragma unroll
          for (int mt = 0; mt < 4; ++mt)
            *(f32x4*)(&lred[((wv * 4 + mt) * 64 + lane) * 4]) = acc[mt];
        }
        __syncthreads();
        if (wv >= 4) {
          #pragma unroll
          for (int mt = 0; mt < 4; ++mt) {
            f32x4* p = (f32x4*)(&lred[(((wv - 4) * 4 + mt) * 64 + lane) * 4]);
            *p += acc[mt];
          }
        }
        __syncthreads();
        {
          const int row = tid >> 3;                 // 0..63
          const int mt = row >> 4, q = (row >> 2) & 3, rr = row & 3;
          const int c0 = (tid & 7) * 2;
          float s0 = 0.f, s1 = 0.f;
          #pragma unroll
          for (int s2 = 0; s2 < 4; ++s2) {
            s0 += lred[((s2 * 4 + mt) * 64 + q * 16 + c0) * 4 + rr];
            s1 += lred[((s2 * 4 + mt) * 64 + q * 16 + c0 + 1) * 4 + rr];
          }
          float* op = ifgo + ((size_t)(l * 64 + row)) * 4096 + bid * 16 + c0;
          union { float f[2]; unsigned long long u; } pk;
          pk.f[0] = s0; pk.f[1] = s1;
          st_dwordx2_sc(op, pk.u);
        }
      }
      arrive(&acnt[l * 16]);               // unconditional (ramp/drain count too)
    }

    // ---------------- phase B: waits its layer's acnt (usually free) ----------------
    if (bid < 192) {
      const int l = bid >> 6, row = bid & 63;
      const int t = s - l;
      waitcnt_ge(&acnt[l * 16], NBLK * (s + 1));
      if (t >= 0 && t < T_STEPS) {
        const float* prow = ifgo + (size_t)(l * 64 + row) * 4096;
        float vv[4][2], actv[4][2];
        #pragma unroll
        for (int g = 0; g < 4; ++g) {
          union { unsigned long long u; float f[2]; } cv;
          cv.u = ld_u64_sc(prow + g * 1024 + tid * 2);
          vv[g][0] = cv.f[0] + bh[l * 4096 + g * 1024 + tid * 2];
          vv[g][1] = cv.f[1] + bh[l * 4096 + g * 1024 + tid * 2 + 1];
        }
        #pragma unroll
        for (int g = 0; g < 4; ++g) {
          float s1 = vv[g][0] + vv[g][1];
          float s2 = vv[g][0] * vv[g][0] + vv[g][1] * vv[g][1];
          reduce2_512(s1, s2, red);
          float mu  = s1 * (1.f / 1024.f);
          float var = fmaxf(s2 * (1.f / 1024.f) - mu * mu, 0.f);
          float inv = rsqrtf(var + EPSV);
          #pragma unroll
          for (int j = 0; j < 2; ++j) {
            int e = g * 1024 + tid * 2 + j;
            actv[g][j] = (vv[g][j] - mu) * inv * ln_g[l * 4096 + e] + ln_b[l * 4096 + e];
          }
        }
        float cn[2];
        {
          float ii0 = sigmoidf_(actv[0][0]), ii1 = sigmoidf_(actv[0][1]);
          float ff0 = sigmoidf_(actv[1][0]), ff1 = sigmoidf_(actv[1][1]);
          float gg0 = tanhf(actv[2][0]),     gg1 = tanhf(actv[2][1]);
          cn[0] = ff0 * c0r + ii0 * gg0;
          cn[1] = ff1 * c1r + ii1 * gg1;
          c0r = cn[0]; c1r = cn[1];
        }
        float s1 = cn[0] + cn[1];
        float s2 = cn[0] * cn[0] + cn[1] * cn[1];
        reduce2_512(s1, s2, red);
        float mu  = s1 * (1.f / 1024.f);
        float var = fmaxf(s2 * (1.f / 1024.f) - mu * mu, 0.f);
        float inv = rsqrtf(var + EPSV);
        float hn[2];
        #pragma unroll
        for (int j = 0; j < 2; ++j) {
          int e = tid * 2 + j;
          float cl = (cn[j] - mu) * inv * lnc_g[l * 1024 + e] + lnc_b[l * 1024 + e];
          hn[j] = sigmoidf_(actv[3][j]) * tanhf(cl);
        }
        union { _Float16 h[2]; unsigned u; } hp;
        hp.h[0] = (_Float16)hn[0]; hp.h[1] = (_Float16)hn[1];
        const int pidx = act_pack_idx(row, tid * 2);
        st_dword_sc(acts + l * 65536 + pidx, hp.u);   // h of layer l -> buf l
        if (l == 2) {
          float* op = out_all + ((size_t)t * BATCH + row) * 1024 + tid * 2;
          op[0] = hn[0]; op[1] = hn[1];    // host-read only
        }
        if (t == T_STEPS - 1) {
          float* hsec = out_all + (size_t)T_STEPS * BATCH * 1024
                        + (size_t)(l * BATCH + row) * 1024 + tid * 2;
          float* csec = hsec + (size_t)NLAYER * BATCH * 1024;
          hsec[0] = hn[0]; hsec[1] = hn[1];
          csec[0] = cn[0]; csec[1] = cn[1];
        }
      }
      arrive(bcnt);                        // unconditional for all 192 B blocks
    }
    waitcnt_ge(bcnt, 192 * (s + 1));       // everyone; gates next copy
  }
}

extern "C" void kernel_launch(void* const* d_in, const int* in_sizes, int n_in,
                              void* d_out, int out_size, void* d_ws, size_t ws_size,
                              hipStream_t stream) {
  const float* x     = (const float*)d_in[0];
  const float* Wx    = (const float*)d_in[1];
  const float* Wh    = (const float*)d_in[2];
  const float* bh    = (const float*)d_in[3];
  const float* ln_g  = (const float*)d_in[4];
  const float* ln_b  = (const float*)d_in[5];
  const float* lnc_g = (const float*)d_in[6];
  const float* lnc_b = (const float*)d_in[7];

  char* ws = (char*)d_ws;
  _Float16* Wpack  = (_Float16*)ws;                              // 50331648 B
  _Float16* xpack  = (_Float16*)(ws + 50331648);                 // 67108864 B (512 x 65536 fp16)
  _Float16* acts   = (_Float16*)(ws + 117440512);                // 393216 B (3 x 65536 fp16)
  float*    ifgo   = (float*)(ws + 117833728);                   // 3145728 B
  int*      flags  = (int*)(ws + 120979456);                     // 36864 B (9216 ints, re-zeroed per call)
  _Float16* xcdbuf = (_Float16*)(ws + 121016320);                // 4194304 B (8 x 512 KB)
  float*    out_all = (float*)d_out;

  hipFuncSetAttribute((const void*)lstm_main,
                      hipFuncAttributeMaxDynamicSharedMemorySize, LDS_BYTES);

  pack_weights<<<98304, 256, 0, stream>>>(Wx, Wh, Wpack);
  pack_x<<<131072, 256, 0, stream>>>(x, xpack);
  init_all<<<804, 256, 0, stream>>>(acts, flags);

  void* args[] = { (void*)&bh, (void*)&ln_g, (void*)&ln_b,
                   (void*)&lnc_g, (void*)&lnc_b, (void*)&Wpack, (void*)&xpack,
                   (void*)&acts, (void*)&xcdbuf, (void*)&ifgo, (void*)&out_all,
                   (void*)&flags };
  hipLaunchCooperativeKernel((void*)lstm_main, dim3(NBLK), dim3(512), args,
                             LDS_BYTES, stream);
}

// Round 23
// 13985.272 us; speedup vs baseline: 1.5218x; 1.5218x over previous
//
#include <hip/hip_runtime.h>
#include <hip/hip_bf16.h>

#define T_STEPS 512
#define BATCH   64
#define HID     1024
#define NLAYER  3
#define EPSV    1e-5f
#define LDS_BYTES 147520
#define NBLK    256

typedef __attribute__((ext_vector_type(8))) short    short8;
typedef __attribute__((ext_vector_type(8))) _Float16 f16x8;
typedef __attribute__((ext_vector_type(4))) float    f32x4;

// packed activation layout within one [64 rows x 1024 k] fp16 buffer (65536 elems):
// [kc(8)][mt(4)][ki(4)][lane(64)][j(8)]  where row = mt*16 + (lane&15),
// k = kc*128 + ki*32 + (lane>>4)*8 + j
__device__ __forceinline__ int act_pack_idx(int row, int k) {
  int mt = row >> 4, lr = row & 15;
  int kc = k >> 7;
  int ki = (k >> 5) & 3;
  int lh = (k >> 3) & 3;
  int j  = k & 7;
  int lane = lr | (lh << 4);
  return ((((kc * 4 + mt) * 4 + ki) * 64) + lane) * 8 + j;
}

__device__ __forceinline__ float sigmoidf_(float v) {
  return 1.f / (1.f + __expf(-v));
}

// ---- write-through (coherent) stores ----
__device__ __forceinline__ void st_dword_sc(void* p, unsigned v) {
  asm volatile("global_store_dword %0, %1, off sc0 sc1"
               :: "v"(p), "v"(v) : "memory");
}
__device__ __forceinline__ void st_dwordx2_sc(void* p, unsigned long long v) {
  asm volatile("global_store_dwordx2 %0, %1, off sc0 sc1"
               :: "v"(p), "v"(v) : "memory");
}
// ---- coherent 8B load (bypasses L1/L2, reads coherence point) ----
__device__ __forceinline__ unsigned long long ld_u64_sc(const void* p) {
  return __hip_atomic_load((const unsigned long long*)p,
                           __ATOMIC_RELAXED, __HIP_MEMORY_SCOPE_SYSTEM);
}

// Global barrier (R12-proven): parallel per-block flag stores, block-0
// aggregation, read-only epoch poll. No cache invalidation anywhere.
// (Counter-RMW rendezvous disproven twice: R8, R22.)
__device__ __forceinline__ void gbar(int* farr, int* epoch, int k) {
  asm volatile("s_waitcnt vmcnt(0)" ::: "memory");
  __syncthreads();
  const int tid = threadIdx.x;
  if (blockIdx.x == 0) {
    if (tid > 0 && tid < NBLK) {
      while (__hip_atomic_load(&farr[tid * 16], __ATOMIC_RELAXED,
                               __HIP_MEMORY_SCOPE_AGENT) < k)
        __builtin_amdgcn_s_sleep(1);
    }
    __syncthreads();
    if (tid == 0)
      __hip_atomic_store(epoch, k, __ATOMIC_RELAXED, __HIP_MEMORY_SCOPE_AGENT);
  } else {
    if (tid == 0) {
      __hip_atomic_store(&farr[blockIdx.x * 16], k, __ATOMIC_RELAXED,
                         __HIP_MEMORY_SCOPE_AGENT);
      while (__hip_atomic_load(epoch, __ATOMIC_RELAXED,
                               __HIP_MEMORY_SCOPE_AGENT) < k)
        __builtin_amdgcn_s_sleep(1);
    }
  }
  __syncthreads();
}

// Wpack per layer: [ncb(64)][kc(16)][nt(4)][ki(4)][lane(64)][j(8)]
__global__ __launch_bounds__(256) void pack_weights(
    const float* __restrict__ Wx, const float* __restrict__ Wh,
    _Float16* __restrict__ Wpack) {
  long idx = (long)blockIdx.x * 256 + threadIdx.x;  // exactly 3*4096*2048 threads
  int l  = (int)(idx / 8388608);
  int r  = (int)(idx % 8388608);
  int ncb = r >> 17;
  int r2 = r & 131071;
  int kc = r2 >> 13;
  int r3 = r2 & 8191;
  int nt = r3 >> 11;
  int r4 = r3 & 2047;
  int ki = r4 >> 9;
  int r5 = r4 & 511;
  int lane = r5 >> 3, j = r5 & 7;
  int n = ncb * 64 + nt * 16 + (lane & 15);
  int k = kc * 128 + ki * 32 + ((lane >> 4) << 3) + j;
  float v = (k < 1024) ? Wx[((size_t)l * 4096 + n) * 1024 + k]
                       : Wh[((size_t)l * 4096 + n) * 1024 + (k - 1024)];
  Wpack[idx] = (_Float16)v;
}

// Pack x for ALL timesteps once. 131072 blocks x 256 threads.
__global__ __launch_bounds__(256) void pack_x(
    const float* __restrict__ x, _Float16* __restrict__ xpack) {
  int i = blockIdx.x * 256 + threadIdx.x;
  int t = i >> 16;
  int r = i & 65535;
  int b = r >> 10, e = r & 1023;
  xpack[(size_t)t * 65536 + act_pack_idx(b, e)] =
      (_Float16)x[((size_t)t * BATCH + b) * 1024 + e];
}

// zero ALL sync state (9216 ints) + zero the 3 h buffers.
// Threads = 9216 + 196608 = 205824 = 804*256 exactly.
__global__ __launch_bounds__(256) void init_all(
    _Float16* __restrict__ acts, int* __restrict__ flags) {
  int i = blockIdx.x * 256 + threadIdx.x;
  if (i < 9216) {
    flags[i] = 0;
  } else {
    ((unsigned short*)acts)[i - 9216] = 0;
  }
}

// sum-reduce two values across 512 threads (8 waves)
__device__ __forceinline__ void reduce2_512(float& a, float& b, float* red) {
  #pragma unroll
  for (int o = 32; o; o >>= 1) {
    a += __shfl_xor(a, o, 64);
    b += __shfl_xor(b, o, 64);
  }
  int wv = threadIdx.x >> 6;
  if ((threadIdx.x & 63) == 0) { red[wv * 2] = a; red[wv * 2 + 1] = b; }
  __syncthreads();
  a = red[0]; b = red[1];
  #pragma unroll
  for (int i = 1; i < 8; ++i) { a += red[i * 2]; b += red[i * 2 + 1]; }
  __syncthreads();
}

// Persistent kernel = R19 minus the copy/xbar staging machinery:
// phase A reads the h-buffers DIRECTLY from acts via sc0sc1 dwordx4 loads
// (L3 truth -- same instruction the copy loop used), layer-0 A from cached
// static xpack. Two parallel-flag gbars per step; no other rendezvous.
// WAR chain: B(s) writes acts after gbar(2s+1); A(s+1) reads after
// gbar(2s+2) -- safe. Both gbars unconditional -- deadlock-free.
__global__ __launch_bounds__(512) __attribute__((amdgpu_waves_per_eu(2, 2)))
void lstm_main(
    const float* __restrict__ bh,
    const float* __restrict__ ln_g, const float* __restrict__ ln_b,
    const float* __restrict__ lnc_g, const float* __restrict__ lnc_b,
    const _Float16* __restrict__ Wpack, const _Float16* __restrict__ xpack,
    _Float16* __restrict__ acts,
    float* __restrict__ ifgo, float* __restrict__ out_all,
    int* __restrict__ flags) {
  extern __shared__ char smem[];
  _Float16* Wlds = (_Float16*)smem;              // [2][64 ks][64 lane][8] = 131072 B
  float*    lred = (float*)(smem + 131072);      // 16384 B
  float*    red  = (float*)(smem + 147456);      // 64 B
  int* epoch = flags + 1;
  int* farr  = flags + 4096;                     // 256 x 16 ints
  const int bid = blockIdx.x, tid = threadIdx.x;
  const int wv = tid >> 6, lane = tid & 63;
  const int ncb = bid >> 2, ntp = bid & 3;

  float c0r = 0.f, c1r = 0.f;   // c-state in registers (fixed B mapping)

  // ---- preload layers 0,1 weight frags into LDS (once) ----
  #pragma unroll
  for (int l = 0; l < 2; ++l)
    #pragma unroll
    for (int i = 0; i < 8; ++i) {
      const int idx = i * 512 + tid;        // 0..4095
      const int ks = idx >> 6, lj = idx & 63;
      const _Float16* src = Wpack
          + ((((size_t)(l * 64 + ncb) * 16 + (ks >> 2)) * 4 + ntp) * 4 + (ks & 3)) * 512
          + lj * 8;
      *(short8*)(Wlds + (l * 64 + ks) * 512 + lj * 8) = *(const short8*)src;
    }
  __syncthreads();

  for (int s = 0; s < T_STEPS + NLAYER - 1; ++s) {
    // ---- W2 streamed weight frags (compiler-scheduled, L3) ----
    f16x8 Wst[8];
    if (s >= 2) {
      #pragma unroll
      for (int i = 0; i < 8; ++i) {
        const int ks = wv * 8 + i;
        Wst[i] = *(const f16x8*)(Wpack
            + ((((size_t)(2 * 64 + ncb) * 16 + (ks >> 2)) * 4 + ntp) * 4 + (ks & 3)) * 512
            + lane * 8);
      }
    }

    // ---------------- phase A: full-K GEMM per layer ----------------
    #pragma unroll
    for (int l = 0; l < 3; ++l) {
      const int t = s - l;
      if (t >= 0 && t < T_STEPS) {
        const bool a_is_x = (l == 0);
        const _Float16* aL = a_is_x ? (xpack + (size_t)t * 65536)
                                    : (acts + (l - 1) * 65536);
        const _Float16* bL = acts + l * 65536;
        f16x8 Wr[8];
        if (l < 2) {
          #pragma unroll
          for (int i = 0; i < 8; ++i)
            Wr[i] = *(const f16x8*)(Wlds + (l * 64 + wv * 8 + i) * 512 + lane * 8);
        } else {
          #pragma unroll
          for (int i = 0; i < 8; ++i) Wr[i] = Wst[i];
        }
        f32x4 acc[4];
        #pragma unroll
        for (int mt = 0; mt < 4; ++mt) acc[mt] = (f32x4){0.f, 0.f, 0.f, 0.f};
        #pragma unroll
        for (int mt = 0; mt < 4; ++mt) {
          f16x8 af[8];
          #pragma unroll
          for (int i = 0; i < 8; ++i) {
            const int ks = wv * 8 + i;           // 0..63
            const _Float16* hb = (ks < 32) ? aL : bL;
            const int ks2 = ks & 31;
            const _Float16* p = hb + (((ks2 >> 2) * 4 + mt) * 4 + (ks2 & 3)) * 512 + lane * 8;
            if (a_is_x && ks < 32) {
              af[i] = *(const f16x8*)p;          // static xpack: plain cached
            } else {
              asm volatile("global_load_dwordx4 %0, %1, off sc0 sc1"  // L3 truth
                           : "=v"(af[i]) : "v"(p));
            }
          }
          asm volatile("s_waitcnt vmcnt(0)" ::: "memory");
          __builtin_amdgcn_sched_barrier(0);
          #pragma unroll
          for (int i = 0; i < 8; ++i)
            acc[mt] = __builtin_amdgcn_mfma_f32_16x16x32_f16(af[i], Wr[i], acc[mt], 0, 0, 0);
        }
        // two-pass cross-wave reduce in 16 KB lred
        __syncthreads();
        if (wv < 4) {
          #pragma unroll
          for (int mt = 0; mt < 4; ++mt)
            *(f32x4*)(&lred[((wv * 4 + mt) * 64 + lane) * 4]) = acc[mt];
        }
        __syncthreads();
        if (wv >= 4) {
          #pragma unroll
          for (int mt = 0; mt < 4; ++mt) {
            f32x4* p = (f32x4*)(&lred[(((wv - 4) * 4 + mt) * 64 + lane) * 4]);
            *p += acc[mt];
          }
        }
        __syncthreads();
        {
          const int row = tid >> 3;                 // 0..63
          const int mt = row >> 4, q = (row >> 2) & 3, rr = row & 3;
          const int c0 = (tid & 7) * 2;
          float s0 = 0.f, s1 = 0.f;
          #pragma unroll
          for (int s2 = 0; s2 < 4; ++s2) {
            s0 += lred[((s2 * 4 + mt) * 64 + q * 16 + c0) * 4 + rr];
            s1 += lred[((s2 * 4 + mt) * 64 + q * 16 + c0 + 1) * 4 + rr];
          }
          float* op = ifgo + ((size_t)(l * 64 + row)) * 4096 + bid * 16 + c0;
          union { float f[2]; unsigned long long u; } pk;
          pk.f[0] = s0; pk.f[1] = s1;
          st_dwordx2_sc(op, pk.u);
        }
      }
    }
    gbar(farr, epoch, 2 * s + 1);

    // ---------------- phase B: bias + LN gates + cell + LN(c) + h ----------------
    if (bid < 192) {
      const int l = bid >> 6, row = bid & 63;
      const int t = s - l;
      if (t >= 0 && t < T_STEPS) {
        const float* prow = ifgo + (size_t)(l * 64 + row) * 4096;
        float vv[4][2], actv[4][2];
        #pragma unroll
        for (int g = 0; g < 4; ++g) {
          union { unsigned long long u; float f[2]; } cv;
          cv.u = ld_u64_sc(prow + g * 1024 + tid * 2);
          vv[g][0] = cv.f[0] + bh[l * 4096 + g * 1024 + tid * 2];
          vv[g][1] = cv.f[1] + bh[l * 4096 + g * 1024 + tid * 2 + 1];
        }
        #pragma unroll
        for (int g = 0; g < 4; ++g) {
          float s1 = vv[g][0] + vv[g][1];
          float s2 = vv[g][0] * vv[g][0] + vv[g][1] * vv[g][1];
          reduce2_512(s1, s2, red);
          float mu  = s1 * (1.f / 1024.f);
          float var = fmaxf(s2 * (1.f / 1024.f) - mu * mu, 0.f);
          float inv = rsqrtf(var + EPSV);
          #pragma unroll
          for (int j = 0; j < 2; ++j) {
            int e = g * 1024 + tid * 2 + j;
            actv[g][j] = (vv[g][j] - mu) * inv * ln_g[l * 4096 + e] + ln_b[l * 4096 + e];
          }
        }
        float cn[2];
        {
          float ii0 = sigmoidf_(actv[0][0]), ii1 = sigmoidf_(actv[0][1]);
          float ff0 = sigmoidf_(actv[1][0]), ff1 = sigmoidf_(actv[1][1]);
          float gg0 = tanhf(actv[2][0]),     gg1 = tanhf(actv[2][1]);
          cn[0] = ff0 * c0r + ii0 * gg0;
          cn[1] = ff1 * c1r + ii1 * gg1;
          c0r = cn[0]; c1r = cn[1];
        }
        float s1 = cn[0] + cn[1];
        float s2 = cn[0] * cn[0] + cn[1] * cn[1];
        reduce2_512(s1, s2, red);
        float mu  = s1 * (1.f / 1024.f);
        float var = fmaxf(s2 * (1.f / 1024.f) - mu * mu, 0.f);
        float inv = rsqrtf(var + EPSV);
        float hn[2];
        #pragma unroll
        for (int j = 0; j < 2; ++j) {
          int e = tid * 2 + j;
          float cl = (cn[j] - mu) * inv * lnc_g[l * 1024 + e] + lnc_b[l * 1024 + e];
          hn[j] = sigmoidf_(actv[3][j]) * tanhf(cl);
        }
        union { _Float16 h[2]; unsigned u; } hp;
        hp.h[0] = (_Float16)hn[0]; hp.h[1] = (_Float16)hn[1];
        const int pidx = act_pack_idx(row, tid * 2);
        st_dword_sc(acts + l * 65536 + pidx, hp.u);   // h of layer l -> buf l
        if (l == 2) {
          float* op = out_all + ((size_t)t * BATCH + row) * 1024 + tid * 2;
          op[0] = hn[0]; op[1] = hn[1];    // host-read only
        }
        if (t == T_STEPS - 1) {
          float* hsec = out_all + (size_t)T_STEPS * BATCH * 1024
                        + (size_t)(l * BATCH + row) * 1024 + tid * 2;
          float* csec = hsec + (size_t)NLAYER * BATCH * 1024;
          hsec[0] = hn[0]; hsec[1] = hn[1];
          csec[0] = cn[0]; csec[1] = cn[1];
        }
      }
    }
    gbar(farr, epoch, 2 * s + 2);
  }
}

extern "C" void kernel_launch(void* const* d_in, const int* in_sizes, int n_in,
                              void* d_out, int out_size, void* d_ws, size_t ws_size,
                              hipStream_t stream) {
  const float* x     = (const float*)d_in[0];
  const float* Wx    = (const float*)d_in[1];
  const float* Wh    = (const float*)d_in[2];
  const float* bh    = (const float*)d_in[3];
  const float* ln_g  = (const float*)d_in[4];
  const float* ln_b  = (const float*)d_in[5];
  const float* lnc_g = (const float*)d_in[6];
  const float* lnc_b = (const float*)d_in[7];

  char* ws = (char*)d_ws;
  _Float16* Wpack  = (_Float16*)ws;                              // 50331648 B
  _Float16* xpack  = (_Float16*)(ws + 50331648);                 // 67108864 B (512 x 65536 fp16)
  _Float16* acts   = (_Float16*)(ws + 117440512);                // 393216 B (3 x 65536 fp16)
  float*    ifgo   = (float*)(ws + 117833728);                   // 3145728 B
  int*      flags  = (int*)(ws + 120979456);                     // 36864 B (9216 ints, re-zeroed per call)
  float*    out_all = (float*)d_out;

  hipFuncSetAttribute((const void*)lstm_main,
                      hipFuncAttributeMaxDynamicSharedMemorySize, LDS_BYTES);

  pack_weights<<<98304, 256, 0, stream>>>(Wx, Wh, Wpack);
  pack_x<<<131072, 256, 0, stream>>>(x, xpack);
  init_all<<<804, 256, 0, stream>>>(acts, flags);

  void* args[] = { (void*)&bh, (void*)&ln_g, (void*)&ln_b,
                   (void*)&lnc_g, (void*)&lnc_b, (void*)&Wpack, (void*)&xpack,
                   (void*)&acts, (void*)&ifgo, (void*)&out_all, (void*)&flags };
  hipLaunchCooperativeKernel((void*)lstm_main, dim3(NBLK), dim3(512), args,
                             LDS_BYTES, stream);
}